// Round 6
// baseline (618.788 us; speedup 1.0000x reference)
//
#include <hip/hip_runtime.h>
#include <hip/hip_bf16.h>
#include <math.h>

// ---------------------------------------------------------------------------
// GPT block fused pipeline, bf16 MFMA. B=4,S=2048,D=1024,H=16,HD=64.
// ws layout (bytes):
//   W1t  @ 0         : 3072x1024 bf16 (W_attn^T)   6291456
//   W2t  @ 6291456   : 1024x1024 bf16 (W_cproj^T)  2097152
//   W3t  @ 8388608   : 4096x1024 bf16 (W_fc^T)     8388608
//   W4t  @ 16777216  : 1024x4096 bf16 (W_mproj^T)  8388608
//   h    @ 25165824  : 8192x1024 bf16 (ln out; later mproj partial0)
//   aout @ 41943040  : 8192x1024 bf16 (attn out; later mproj partial1)
//   big  @ 58720256  : 8192x3072 bf16 qkv; then cproj partials; then fc-act
//   total 125829120 bytes.  x2 (residual after attn) lives in d_out (fp32).
// cproj & mproj are K-split x2 (grid z): BN=128 grid would be 512 blocks =
// 2/CU (grid-limited — r4 post-mortem). All GEMMs use an XCD-affine swizzle
// (m-strip ≡ xcd mod 8) so each XCD's L2 only services 8 A-strips — r5 showed
// naive order thrashes L2 (FETCH 287 MB vs 72 ideal on mproj).
// ---------------------------------------------------------------------------

typedef __attribute__((ext_vector_type(8))) short short8;
typedef __attribute__((ext_vector_type(4))) float floatx4;

#define MFMA16(a, b, c) __builtin_amdgcn_mfma_f32_16x16x32_bf16((a), (b), (c), 0, 0, 0)

__device__ __forceinline__ short f2bf(float f) {
    union { float f; unsigned u; } a; a.f = f;
    unsigned r = a.u + 0x7fffu + ((a.u >> 16) & 1u);   // round-to-nearest-even
    return (short)(r >> 16);
}

__device__ __forceinline__ float bf2f(unsigned short u) {
    union { unsigned u; float f; } a; a.u = ((unsigned)u) << 16;
    return a.f;
}

__device__ __forceinline__ float fast_rcp(float x) {
#if defined(__HIP_DEVICE_COMPILE__)
    return __builtin_amdgcn_rcpf(x);
#else
    return 1.0f / x;
#endif
}

// gelu(x) = 0.5x(1+tanh(u)) = x - x/(e^{2u}+1),  u = 0.79788456(x+0.044715x^3)
__device__ __forceinline__ float gelu_f(float x) {
    const float u = x + 0.044715f * x * x * x;
    const float t = exp2f(2.302118131f * u);   // 2*0.79788456*log2(e)*u
    return x - x * fast_rcp(t + 1.0f);
}

__device__ __forceinline__ void gload_lds16(const short* g, short* l) {
    __builtin_amdgcn_global_load_lds((const __attribute__((address_space(1))) void*)g,
                                     (__attribute__((address_space(3))) void*)l, 16, 0, 0);
}

// ---------------- transpose + cast fp32 W[K][N] -> bf16 Wt[N][K] -------------
__global__ void tcast_kernel(const float* __restrict__ W, short* __restrict__ Wt,
                             int K, int N) {
    __shared__ float tile[32][33];
    const int bx = blockIdx.x * 32;  // n
    const int by = blockIdx.y * 32;  // k
    const int tx = threadIdx.x;      // 0..31
    const int ty = threadIdx.y;      // 0..7
#pragma unroll
    for (int i = 0; i < 32; i += 8)
        tile[ty + i][tx] = W[(size_t)(by + ty + i) * N + bx + tx];
    __syncthreads();
#pragma unroll
    for (int i = 0; i < 32; i += 8)
        Wt[(size_t)(bx + ty + i) * K + by + tx] = f2bf(tile[tx][ty + i]);
}

// ---------------- LayerNorm: fp32 [8192][1024] -> bf16 ----------------------
__global__ __launch_bounds__(256) void ln_kernel(const float* __restrict__ x,
                                                 const float* __restrict__ w,
                                                 const float* __restrict__ b,
                                                 short* __restrict__ out) {
    const int row = blockIdx.x;
    const int t = threadIdx.x;
    const float4 v = ((const float4*)(x + (size_t)row * 1024))[t];
    float s = v.x + v.y + v.z + v.w;
    float s2 = v.x * v.x + v.y * v.y + v.z * v.z + v.w * v.w;
#pragma unroll
    for (int d = 32; d >= 1; d >>= 1) {
        s += __shfl_xor(s, d, 64);
        s2 += __shfl_xor(s2, d, 64);
    }
    __shared__ float red[8];
    const int wid = t >> 6, lane = t & 63;
    if (lane == 0) { red[wid * 2] = s; red[wid * 2 + 1] = s2; }
    __syncthreads();
    s = red[0] + red[2] + red[4] + red[6];
    s2 = red[1] + red[3] + red[5] + red[7];
    const float mean = s * (1.f / 1024.f);
    const float var = s2 * (1.f / 1024.f) - mean * mean;
    const float rstd = rsqrtf(var + 1e-5f);
    const float4 wv = ((const float4*)w)[t];
    const float4 bv = ((const float4*)b)[t];
    union { ushort4 u; short sa[4]; } ov;
    ov.sa[0] = f2bf(wv.x * ((v.x - mean) * rstd) + bv.x);
    ov.sa[1] = f2bf(wv.y * ((v.y - mean) * rstd) + bv.y);
    ov.sa[2] = f2bf(wv.z * ((v.z - mean) * rstd) + bv.z);
    ov.sa[3] = f2bf(wv.w * ((v.w - mean) * rstd) + bv.w);
    ((ushort4*)(out + (size_t)row * 1024))[t] = ov.u;
}

// ------- reduce: out = bf16(p0) + bf16(p1) + bias + res (all [8192][1024]) ---
__global__ __launch_bounds__(256) void reduce_kernel(
    const unsigned short* __restrict__ p0, const unsigned short* __restrict__ p1,
    const float* __restrict__ bias, const float* __restrict__ res,
    float* __restrict__ out) {
    const int row = blockIdx.x;
    const int t = threadIdx.x;
    const size_t off = (size_t)row * 1024;
    const ushort4 a = ((const ushort4*)(p0 + off))[t];
    const ushort4 c = ((const ushort4*)(p1 + off))[t];
    const float4 r = ((const float4*)(res + off))[t];
    const float4 bv = ((const float4*)bias)[t];
    float4 o;
    o.x = bf2f(a.x) + bf2f(c.x) + bv.x + r.x;
    o.y = bf2f(a.y) + bf2f(c.y) + bv.y + r.y;
    o.z = bf2f(a.z) + bf2f(c.z) + bv.z + r.z;
    o.w = bf2f(a.w) + bf2f(c.w) + bv.w + r.w;
    ((float4*)(out + off))[t] = o;
}

// ---------------- GEMM: C[M][N] = A[M][K] @ Bt[N][K]^T + bias, epilogues -----
// EPI 0: +bias -> bf16.  EPI 1: gelu(+bias) -> bf16.
// EPI 3: raw partial -> bf16 at Cout + z*M*N (K-split partials, no bias).
// Requires gridDim.y == 64.  XCD-affine swizzle: linear block id mod 8 picks
// the XCD (HW round-robin heuristic); m-strip ≡ xcd (mod 8) so each XCD's L2
// only services 8 of the 64 A m-strips.
template <int EPI>
__global__ __launch_bounds__(256) void gemm_kernel(
    const short* __restrict__ A, const short* __restrict__ Bt,
    const float* __restrict__ bias,
    void* __restrict__ Cout, int M, int N, int Klen, int lda, int ldb) {
    __shared__ __align__(16) short As[128][32];
    __shared__ __align__(16) short Bs[128][32];

    const int tid = threadIdx.x;
    const int wid = tid >> 6;
    const int lane = tid & 63;
    const int quad = lane >> 4;
    const int l16 = lane & 15;
    const int wm = (wid >> 1) * 64;
    const int wn = (wid & 1) * 64;

    const unsigned gx = gridDim.x;
    const unsigned bid2 = blockIdx.x + gx * blockIdx.y;
    const unsigned xcd = bid2 & 7;
    const unsigned loc = bid2 >> 3;
    const unsigned nb = loc % gx;
    const unsigned mhi = loc / gx;            // 0..7
    const int m0 = (int)(mhi * 8 + xcd) * 128;
    const int n0 = (int)nb * 128;
    const int kbase = blockIdx.z * Klen;

    const int lr = lane >> 2;        // row within 16-row wave slab
    const int lc = (lane & 3) * 8;   // short offset within 32-wide row

    floatx4 acc[4][4] = {};

    const short* ga0 = A + (size_t)(m0 + wid * 16 + lr) * lda + kbase + lc;
    const short* ga1 = A + (size_t)(m0 + 64 + wid * 16 + lr) * lda + kbase + lc;
    const short* gb0 = Bt + (size_t)(n0 + wid * 16 + lr) * ldb + kbase + lc;
    const short* gb1 = Bt + (size_t)(n0 + 64 + wid * 16 + lr) * ldb + kbase + lc;
    short* lA0 = &As[wid * 16][0];
    short* lA1 = &As[64 + wid * 16][0];
    short* lB0 = &Bs[wid * 16][0];
    short* lB1 = &Bs[64 + wid * 16][0];

    for (int k0 = 0; k0 < Klen; k0 += 32) {
        gload_lds16(ga0 + k0, lA0);
        gload_lds16(ga1 + k0, lA1);
        gload_lds16(gb0 + k0, lB0);
        gload_lds16(gb1 + k0, lB1);
        __syncthreads();
        short8 af[4], bf[4];
#pragma unroll
        for (int mt = 0; mt < 4; mt++)
            af[mt] = *(const short8*)&As[wm + mt * 16 + l16][quad * 8];
#pragma unroll
        for (int nt = 0; nt < 4; nt++)
            bf[nt] = *(const short8*)&Bs[wn + nt * 16 + l16][quad * 8];
#pragma unroll
        for (int mt = 0; mt < 4; mt++)
#pragma unroll
            for (int nt = 0; nt < 4; nt++)
                acc[mt][nt] = MFMA16(af[mt], bf[nt], acc[mt][nt]);
        __syncthreads();
    }
#pragma unroll
    for (int nt = 0; nt < 4; nt++) {
        const int col = n0 + wn + nt * 16 + l16;
        const float bv = (EPI == 3) ? 0.f : bias[col];
#pragma unroll
        for (int mt = 0; mt < 4; mt++) {
#pragma unroll
            for (int r = 0; r < 4; r++) {
                const int row = m0 + wm + mt * 16 + quad * 4 + r;
                const size_t idx = (size_t)row * N + col;
                float v = acc[mt][nt][r] + bv;
                if constexpr (EPI == 0) {
                    ((short*)Cout)[idx] = f2bf(v);
                } else if constexpr (EPI == 1) {
                    ((short*)Cout)[idx] = f2bf(gelu_f(v));
                } else {
                    ((short*)Cout)[(size_t)blockIdx.z * M * N + idx] = f2bf(v);
                }
            }
        }
    }
}

// ---------------- causal flash attention (S^T formulation) -------------------
// qkv bf16 [B=4][S=2048][3072] (q|k|v each 1024 = 16 heads x 64)
// out bf16 [B][S][1024].
// S^T = K·Q^T via mfma(A=K, B=Q): C-layout puts q on lanes (col=l16), keys on
// quad*4+r -> softmax over keys is in-register + 2 shuffles; per-q state is
// per-lane. P^T (C-layout) feeds PV directly via the key remap
// key(quad*8+j) = c*32 + (j<4 ? quad*4+j : 16+quad*4+j-4); V^T A-operand
// gathered from LDS at those keys. O^T -> O via per-wave LDS transpose.
__global__ __launch_bounds__(256) void attn_kernel(const short* __restrict__ qkv,
                                                   short* __restrict__ aout) {
    __shared__ __align__(16) short smem[9216];   // Ks[64][72] | Vs[64][68]; reused as Ow
    short* Ks = smem;               // stride 72
    short* Vs = smem + 64 * 72;     // stride 68: u16 column reads conflict-free

    const int tid = threadIdx.x;
    const int wid = tid >> 6;
    const int lane = tid & 63;
    const int quad = lane >> 4;
    const int l16 = lane & 15;

    const int qtile = 15 - blockIdx.y;      // longest (most k-tiles) blocks first
    const int q0 = qtile * 128;
    const int bh = blockIdx.x;
    const int b = bh >> 4;
    const int h = bh & 15;

    const short* base = qkv + (size_t)b * 2048 * 3072 + h * 64;
    const int qrow_base = q0 + wid * 32;

    short8 qf[2][2];
#pragma unroll
    for (int qt = 0; qt < 2; qt++)
#pragma unroll
        for (int ks = 0; ks < 2; ks++)
            qf[qt][ks] = *(const short8*)(base +
                (size_t)(qrow_base + qt * 16 + l16) * 3072 + ks * 32 + quad * 8);

    floatx4 o[4][2] = {};           // O^T: [dt][qt], row d=dt*16+quad*4+r, col q=l16
    float mrow[2] = {-1e30f, -1e30f};
    float lrow[2] = {0.f, 0.f};
    const float SCL = 0.125f * 1.44269504f;  // 1/sqrt(64) * log2(e); softmax in base-2

    const int nkt = qtile * 2 + 2;
    for (int kt = 0; kt < nkt; kt++) {
        const int kt0 = kt * 64;
        {   // stage K[64][64] and V[64][64] (row-major, padded, coalesced)
            const int r = tid >> 2;
            const int cg = (tid & 3) * 16;
            const short* krow = base + (size_t)(kt0 + r) * 3072 + 1024 + cg;
            const short* vrow = base + (size_t)(kt0 + r) * 3072 + 2048 + cg;
            *(uint4*)&Ks[r * 72 + cg] = ((const uint4*)krow)[0];
            *(uint4*)&Ks[r * 72 + cg + 8] = ((const uint4*)krow)[1];
            *(uint2*)&Vs[r * 68 + cg] = ((const uint2*)vrow)[0];
            *(uint2*)&Vs[r * 68 + cg + 4] = ((const uint2*)vrow)[1];
            *(uint2*)&Vs[r * 68 + cg + 8] = ((const uint2*)vrow)[2];
            *(uint2*)&Vs[r * 68 + cg + 12] = ((const uint2*)vrow)[3];
        }
        __syncthreads();
        if (kt0 <= qrow_base + 31) {
            floatx4 st[4][2] = {};
#pragma unroll
            for (int kti = 0; kti < 4; kti++) {
                const short8 kf0 = *(const short8*)&Ks[(kti * 16 + l16) * 72 + quad * 8];
                const short8 kf1 = *(const short8*)&Ks[(kti * 16 + l16) * 72 + 32 + quad * 8];
#pragma unroll
                for (int qt = 0; qt < 2; qt++) {
                    st[kti][qt] = MFMA16(kf0, qf[qt][0], st[kti][qt]);
                    st[kti][qt] = MFMA16(kf1, qf[qt][1], st[kti][qt]);
                }
            }
            const bool needmask = (kt0 + 63) > qrow_base;
            short8 pk[2][2];   // [chunk c][qt]: B-operand for PV (packed kti pair)
#pragma unroll
            for (int qt = 0; qt < 2; qt++) {
                const int q = qrow_base + qt * 16 + l16;
#pragma unroll
                for (int kti = 0; kti < 4; kti++)
#pragma unroll
                    for (int r = 0; r < 4; r++) {
                        float v = st[kti][qt][r] * SCL;
                        if (needmask && (kt0 + kti * 16 + quad * 4 + r) > q) v = -1e30f;
                        st[kti][qt][r] = v;
                    }
                float mx = -1e30f;
#pragma unroll
                for (int kti = 0; kti < 4; kti++)
#pragma unroll
                    for (int r = 0; r < 4; r++) mx = fmaxf(mx, st[kti][qt][r]);
                mx = fmaxf(mx, __shfl_xor(mx, 16, 64));
                mx = fmaxf(mx, __shfl_xor(mx, 32, 64));
                const float mnew = fmaxf(mrow[qt], mx);
                const float alpha = exp2f(mrow[qt] - mnew);
                mrow[qt] = mnew;
                float ps = 0.f;
#pragma unroll
                for (int kti = 0; kti < 4; kti++)
#pragma unroll
                    for (int r = 0; r < 4; r++) {
                        const float p = exp2f(st[kti][qt][r] - mnew);
                        st[kti][qt][r] = p;
                        ps += p;
                    }
                ps += __shfl_xor(ps, 16, 64);
                ps += __shfl_xor(ps, 32, 64);
                lrow[qt] = lrow[qt] * alpha + ps;
#pragma unroll
                for (int dt = 0; dt < 4; dt++) o[dt][qt] *= alpha;
#pragma unroll
                for (int kti = 0; kti < 4; kti++)
#pragma unroll
                    for (int r = 0; r < 4; r++)
                        pk[kti >> 1][qt][(kti & 1) * 4 + r] = f2bf(st[kti][qt][r]);
            }
#pragma unroll
            for (int c = 0; c < 2; c++)
#pragma unroll
                for (int dt = 0; dt < 4; dt++) {
                    short8 vf;
#pragma unroll
                    for (int j = 0; j < 4; j++) {
                        vf[j]     = Vs[(c * 32 + quad * 4 + j) * 68 + dt * 16 + l16];
                        vf[4 + j] = Vs[(c * 32 + 16 + quad * 4 + j) * 68 + dt * 16 + l16];
                    }
                    o[dt][0] = MFMA16(vf, pk[c][0], o[dt][0]);
                    o[dt][1] = MFMA16(vf, pk[c][1], o[dt][1]);
                }
        }
        __syncthreads();
    }
    // epilogue: normalize, per-wave transpose O^T->O through LDS, coalesced store
    short* Ow = smem + wid * (32 * 72);   // [32 q][72 stride]
    const float rl0 = 1.0f / lrow[0];
    const float rl1 = 1.0f / lrow[1];
#pragma unroll
    for (int dt = 0; dt < 4; dt++)
#pragma unroll
        for (int r = 0; r < 4; r++) {
            Ow[(l16) * 72 + dt * 16 + quad * 4 + r] = f2bf(o[dt][0][r] * rl0);
            Ow[(16 + l16) * 72 + dt * 16 + quad * 4 + r] = f2bf(o[dt][1][r] * rl1);
        }
    __asm__ volatile("s_waitcnt lgkmcnt(0)" ::: "memory");
    {
        const int ql = lane >> 1;          // 0..31
        const int h2 = lane & 1;           // which 64B half of the row
        short* orow = aout + (size_t)(b * 2048 + q0 + wid * 32 + ql) * 1024 + h * 64 + h2 * 32;
#pragma unroll
        for (int s = 0; s < 4; s++)
            *(uint4*)(orow + s * 8) = *(const uint4*)&Ow[ql * 72 + h2 * 32 + s * 8];
    }
}

// ---------------------------------------------------------------------------
extern "C" void kernel_launch(void* const* d_in, const int* in_sizes, int n_in,
                              void* d_out, int out_size, void* d_ws, size_t ws_size,
                              hipStream_t stream) {
    const float* x       = (const float*)d_in[0];
    const float* ln1_w   = (const float*)d_in[1];
    const float* ln1_b   = (const float*)d_in[2];
    const float* W_attn  = (const float*)d_in[3];
    const float* b_attn  = (const float*)d_in[4];
    const float* W_cproj = (const float*)d_in[5];
    const float* b_cproj = (const float*)d_in[6];
    const float* ln2_w   = (const float*)d_in[7];
    const float* ln2_b   = (const float*)d_in[8];
    const float* W_fc    = (const float*)d_in[9];
    const float* b_fc    = (const float*)d_in[10];
    const float* W_mproj = (const float*)d_in[11];
    const float* b_mproj = (const float*)d_in[12];

    char* ws = (char*)d_ws;
    short* W1t  = (short*)(ws + 0);
    short* W2t  = (short*)(ws + 6291456);
    short* W3t  = (short*)(ws + 8388608);
    short* W4t  = (short*)(ws + 16777216);
    short* h    = (short*)(ws + 25165824);
    short* aout = (short*)(ws + 41943040);
    short* big  = (short*)(ws + 58720256);   // qkv / cproj partials / fc-act
    short* pbuf = h;                         // mproj partials [2][8192][1024] (h+aout, dead)
    float* x2   = (float*)d_out;             // residual after attn lives in d_out
    float* out  = (float*)d_out;

    dim3 tb(32, 8);
    hipLaunchKernelGGL(tcast_kernel, dim3(96, 32), tb, 0, stream, W_attn, W1t, 1024, 3072);
    hipLaunchKernelGGL(tcast_kernel, dim3(32, 32), tb, 0, stream, W_cproj, W2t, 1024, 1024);
    hipLaunchKernelGGL(tcast_kernel, dim3(128, 32), tb, 0, stream, W_fc, W3t, 1024, 4096);
    hipLaunchKernelGGL(tcast_kernel, dim3(32, 128), tb, 0, stream, W_mproj, W4t, 4096, 1024);

    hipLaunchKernelGGL(ln_kernel, dim3(8192), dim3(256), 0, stream, x, ln1_w, ln1_b, h);

    hipLaunchKernelGGL((gemm_kernel<0>), dim3(24, 64, 1), dim3(256), 0, stream,
                       h, W1t, b_attn, (void*)big,
                       8192, 3072, 1024, 1024, 1024);

    hipLaunchKernelGGL(attn_kernel, dim3(64, 16), dim3(256), 0, stream, big, aout);

    // cproj: K-split x2 -> bf16 partials in big (qkv is dead), then reduce.
    hipLaunchKernelGGL((gemm_kernel<3>), dim3(8, 64, 2), dim3(256), 0, stream,
                       aout, W2t, (const float*)nullptr, (void*)big,
                       8192, 1024, 512, 1024, 1024);
    hipLaunchKernelGGL(reduce_kernel, dim3(8192), dim3(256), 0, stream,
                       (const unsigned short*)big,
                       (const unsigned short*)(big + (size_t)8192 * 1024),
                       b_cproj, x, x2);

    hipLaunchKernelGGL(ln_kernel, dim3(8192), dim3(256), 0, stream, x2, ln2_w, ln2_b, h);

    hipLaunchKernelGGL((gemm_kernel<1>), dim3(32, 64, 1), dim3(256), 0, stream,
                       h, W3t, b_fc, (void*)big,
                       8192, 4096, 1024, 1024, 1024);

    // mproj: K-split x2 -> bf16 partials (h+aout region), then fused reduce.
    hipLaunchKernelGGL((gemm_kernel<3>), dim3(8, 64, 2), dim3(256), 0, stream,
                       big, W4t, (const float*)nullptr, (void*)pbuf,
                       8192, 1024, 2048, 4096, 4096);
    hipLaunchKernelGGL(reduce_kernel, dim3(8192), dim3(256), 0, stream,
                       (const unsigned short*)pbuf,
                       (const unsigned short*)(pbuf + (size_t)8192 * 1024),
                       b_mproj, x2, out);
}

// Round 7
// 603.542 us; speedup vs baseline: 1.0253x; 1.0253x over previous
//
#include <hip/hip_runtime.h>
#include <hip/hip_bf16.h>
#include <math.h>

// ---------------------------------------------------------------------------
// GPT block fused pipeline, bf16 MFMA. B=4,S=2048,D=1024,H=16,HD=64.
// ws layout (bytes):
//   W1t  @ 0         : 3072x1024 bf16 (W_attn^T)   6291456
//   W2t  @ 6291456   : 1024x1024 bf16 (W_cproj^T)  2097152
//   W3t  @ 8388608   : 4096x1024 bf16 (W_fc^T)     8388608
//   W4t  @ 16777216  : 1024x4096 bf16 (W_mproj^T)  8388608
//   h    @ 25165824  : 8192x1024 bf16 (ln out; attn chunk0 partials; mproj p0)
//   aout @ 41943040  : 8192x1024 bf16 (attn out; mproj partial1)
//   big  @ 58720256  : 8192x3072 bf16 qkv; then cproj partials; then fc-act
//   total 125829120 bytes.  x2 (residual after attn) lives in d_out (fp32).
// Attention is flash-decoding split: any block runs <=16 k-tiles; qt8-15 are
// split at key 1024 into two partial blocks (unnormalized O', m, l) merged by
// a combine kernel — kills the 32-ktile straggler tail (r6: attn 130us,
// occupancy 19%, tail-bound).
// ---------------------------------------------------------------------------

typedef __attribute__((ext_vector_type(8))) short short8;
typedef __attribute__((ext_vector_type(4))) float floatx4;

#define MFMA16(a, b, c) __builtin_amdgcn_mfma_f32_16x16x32_bf16((a), (b), (c), 0, 0, 0)

__device__ __forceinline__ short f2bf(float f) {
    union { float f; unsigned u; } a; a.f = f;
    unsigned r = a.u + 0x7fffu + ((a.u >> 16) & 1u);   // round-to-nearest-even
    return (short)(r >> 16);
}

__device__ __forceinline__ float bf2f(unsigned short u) {
    union { unsigned u; float f; } a; a.u = ((unsigned)u) << 16;
    return a.f;
}

__device__ __forceinline__ float fast_rcp(float x) {
#if defined(__HIP_DEVICE_COMPILE__)
    return __builtin_amdgcn_rcpf(x);
#else
    return 1.0f / x;
#endif
}

// gelu(x) = 0.5x(1+tanh(u)) = x - x/(e^{2u}+1),  u = 0.79788456(x+0.044715x^3)
__device__ __forceinline__ float gelu_f(float x) {
    const float u = x + 0.044715f * x * x * x;
    const float t = exp2f(2.302118131f * u);   // 2*0.79788456*log2(e)*u
    return x - x * fast_rcp(t + 1.0f);
}

__device__ __forceinline__ void gload_lds16(const short* g, short* l) {
    __builtin_amdgcn_global_load_lds((const __attribute__((address_space(1))) void*)g,
                                     (__attribute__((address_space(3))) void*)l, 16, 0, 0);
}

// ---------------- transpose + cast fp32 W[K][N] -> bf16 Wt[N][K] -------------
__global__ void tcast_kernel(const float* __restrict__ W, short* __restrict__ Wt,
                             int K, int N) {
    __shared__ float tile[32][33];
    const int bx = blockIdx.x * 32;  // n
    const int by = blockIdx.y * 32;  // k
    const int tx = threadIdx.x;      // 0..31
    const int ty = threadIdx.y;      // 0..7
#pragma unroll
    for (int i = 0; i < 32; i += 8)
        tile[ty + i][tx] = W[(size_t)(by + ty + i) * N + bx + tx];
    __syncthreads();
#pragma unroll
    for (int i = 0; i < 32; i += 8)
        Wt[(size_t)(bx + ty + i) * K + by + tx] = f2bf(tile[tx][ty + i]);
}

// ---------------- LayerNorm: fp32 [8192][1024] -> bf16 ----------------------
__global__ __launch_bounds__(256) void ln_kernel(const float* __restrict__ x,
                                                 const float* __restrict__ w,
                                                 const float* __restrict__ b,
                                                 short* __restrict__ out) {
    const int row = blockIdx.x;
    const int t = threadIdx.x;
    const float4 v = ((const float4*)(x + (size_t)row * 1024))[t];
    float s = v.x + v.y + v.z + v.w;
    float s2 = v.x * v.x + v.y * v.y + v.z * v.z + v.w * v.w;
#pragma unroll
    for (int d = 32; d >= 1; d >>= 1) {
        s += __shfl_xor(s, d, 64);
        s2 += __shfl_xor(s2, d, 64);
    }
    __shared__ float red[8];
    const int wid = t >> 6, lane = t & 63;
    if (lane == 0) { red[wid * 2] = s; red[wid * 2 + 1] = s2; }
    __syncthreads();
    s = red[0] + red[2] + red[4] + red[6];
    s2 = red[1] + red[3] + red[5] + red[7];
    const float mean = s * (1.f / 1024.f);
    const float var = s2 * (1.f / 1024.f) - mean * mean;
    const float rstd = rsqrtf(var + 1e-5f);
    const float4 wv = ((const float4*)w)[t];
    const float4 bv = ((const float4*)b)[t];
    union { ushort4 u; short sa[4]; } ov;
    ov.sa[0] = f2bf(wv.x * ((v.x - mean) * rstd) + bv.x);
    ov.sa[1] = f2bf(wv.y * ((v.y - mean) * rstd) + bv.y);
    ov.sa[2] = f2bf(wv.z * ((v.z - mean) * rstd) + bv.z);
    ov.sa[3] = f2bf(wv.w * ((v.w - mean) * rstd) + bv.w);
    ((ushort4*)(out + (size_t)row * 1024))[t] = ov.u;
}

// ------- reduce: out = bf16(p0) + bf16(p1) + bias + res (all [8192][1024]) ---
__global__ __launch_bounds__(256) void reduce_kernel(
    const unsigned short* __restrict__ p0, const unsigned short* __restrict__ p1,
    const float* __restrict__ bias, const float* __restrict__ res,
    float* __restrict__ out) {
    const int row = blockIdx.x;
    const int t = threadIdx.x;
    const size_t off = (size_t)row * 1024;
    const ushort4 a = ((const ushort4*)(p0 + off))[t];
    const ushort4 c = ((const ushort4*)(p1 + off))[t];
    const float4 r = ((const float4*)(res + off))[t];
    const float4 bv = ((const float4*)bias)[t];
    float4 o;
    o.x = bf2f(a.x) + bf2f(c.x) + bv.x + r.x;
    o.y = bf2f(a.y) + bf2f(c.y) + bv.y + r.y;
    o.z = bf2f(a.z) + bf2f(c.z) + bv.z + r.z;
    o.w = bf2f(a.w) + bf2f(c.w) + bv.w + r.w;
    ((float4*)(out + off))[t] = o;
}

// ------- fused: x2 = p0+p1+bias+res;  h = LN(x2)*w+b (saves a full pass) -----
__global__ __launch_bounds__(256) void reduce_ln_kernel(
    const unsigned short* __restrict__ p0, const unsigned short* __restrict__ p1,
    const float* __restrict__ bias, const float* __restrict__ res,
    float* __restrict__ x2out,
    const float* __restrict__ w, const float* __restrict__ b,
    short* __restrict__ hout) {
    const int row = blockIdx.x;
    const int t = threadIdx.x;
    const size_t off = (size_t)row * 1024;
    const ushort4 a = ((const ushort4*)(p0 + off))[t];
    const ushort4 c = ((const ushort4*)(p1 + off))[t];
    const float4 r = ((const float4*)(res + off))[t];
    const float4 bv = ((const float4*)bias)[t];
    float4 v;
    v.x = bf2f(a.x) + bf2f(c.x) + bv.x + r.x;
    v.y = bf2f(a.y) + bf2f(c.y) + bv.y + r.y;
    v.z = bf2f(a.z) + bf2f(c.z) + bv.z + r.z;
    v.w = bf2f(a.w) + bf2f(c.w) + bv.w + r.w;
    ((float4*)(x2out + off))[t] = v;
    float s = v.x + v.y + v.z + v.w;
    float s2 = v.x * v.x + v.y * v.y + v.z * v.z + v.w * v.w;
#pragma unroll
    for (int d = 32; d >= 1; d >>= 1) {
        s += __shfl_xor(s, d, 64);
        s2 += __shfl_xor(s2, d, 64);
    }
    __shared__ float red[8];
    const int wid = t >> 6, lane = t & 63;
    if (lane == 0) { red[wid * 2] = s; red[wid * 2 + 1] = s2; }
    __syncthreads();
    s = red[0] + red[2] + red[4] + red[6];
    s2 = red[1] + red[3] + red[5] + red[7];
    const float mean = s * (1.f / 1024.f);
    const float var = s2 * (1.f / 1024.f) - mean * mean;
    const float rstd = rsqrtf(var + 1e-5f);
    const float4 wv = ((const float4*)w)[t];
    const float4 lb = ((const float4*)b)[t];
    union { ushort4 u; short sa[4]; } ov;
    ov.sa[0] = f2bf(wv.x * ((v.x - mean) * rstd) + lb.x);
    ov.sa[1] = f2bf(wv.y * ((v.y - mean) * rstd) + lb.y);
    ov.sa[2] = f2bf(wv.z * ((v.z - mean) * rstd) + lb.z);
    ov.sa[3] = f2bf(wv.w * ((v.w - mean) * rstd) + lb.w);
    ((ushort4*)(hout + (size_t)row * 1024))[t] = ov.u;
}

// ---------------- GEMM: C[M][N] = A[M][K] @ Bt[N][K]^T + bias, epilogues -----
// EPI 0: +bias -> bf16.  EPI 1: gelu(+bias) -> bf16.
// EPI 3: raw partial -> bf16 at Cout + z*M*N (K-split partials, no bias).
// Requires gridDim.y == 64.  XCD-affine swizzle (m-strip ≡ xcd mod 8).
template <int EPI>
__global__ __launch_bounds__(256) void gemm_kernel(
    const short* __restrict__ A, const short* __restrict__ Bt,
    const float* __restrict__ bias,
    void* __restrict__ Cout, int M, int N, int Klen, int lda, int ldb) {
    __shared__ __align__(16) short As[128][32];
    __shared__ __align__(16) short Bs[128][32];

    const int tid = threadIdx.x;
    const int wid = tid >> 6;
    const int lane = tid & 63;
    const int quad = lane >> 4;
    const int l16 = lane & 15;
    const int wm = (wid >> 1) * 64;
    const int wn = (wid & 1) * 64;

    const unsigned gx = gridDim.x;
    const unsigned bid2 = blockIdx.x + gx * blockIdx.y;
    const unsigned xcd = bid2 & 7;
    const unsigned loc = bid2 >> 3;
    const unsigned nb = loc % gx;
    const unsigned mhi = loc / gx;            // 0..7
    const int m0 = (int)(mhi * 8 + xcd) * 128;
    const int n0 = (int)nb * 128;
    const int kbase = blockIdx.z * Klen;

    const int lr = lane >> 2;
    const int lc = (lane & 3) * 8;

    floatx4 acc[4][4] = {};

    const short* ga0 = A + (size_t)(m0 + wid * 16 + lr) * lda + kbase + lc;
    const short* ga1 = A + (size_t)(m0 + 64 + wid * 16 + lr) * lda + kbase + lc;
    const short* gb0 = Bt + (size_t)(n0 + wid * 16 + lr) * ldb + kbase + lc;
    const short* gb1 = Bt + (size_t)(n0 + 64 + wid * 16 + lr) * ldb + kbase + lc;
    short* lA0 = &As[wid * 16][0];
    short* lA1 = &As[64 + wid * 16][0];
    short* lB0 = &Bs[wid * 16][0];
    short* lB1 = &Bs[64 + wid * 16][0];

    for (int k0 = 0; k0 < Klen; k0 += 32) {
        gload_lds16(ga0 + k0, lA0);
        gload_lds16(ga1 + k0, lA1);
        gload_lds16(gb0 + k0, lB0);
        gload_lds16(gb1 + k0, lB1);
        __syncthreads();
        short8 af[4], bf[4];
#pragma unroll
        for (int mt = 0; mt < 4; mt++)
            af[mt] = *(const short8*)&As[wm + mt * 16 + l16][quad * 8];
#pragma unroll
        for (int nt = 0; nt < 4; nt++)
            bf[nt] = *(const short8*)&Bs[wn + nt * 16 + l16][quad * 8];
#pragma unroll
        for (int mt = 0; mt < 4; mt++)
#pragma unroll
            for (int nt = 0; nt < 4; nt++)
                acc[mt][nt] = MFMA16(af[mt], bf[nt], acc[mt][nt]);
        __syncthreads();
    }
#pragma unroll
    for (int nt = 0; nt < 4; nt++) {
        const int col = n0 + wn + nt * 16 + l16;
        const float bv = (EPI == 3) ? 0.f : bias[col];
#pragma unroll
        for (int mt = 0; mt < 4; mt++) {
#pragma unroll
            for (int r = 0; r < 4; r++) {
                const int row = m0 + wm + mt * 16 + quad * 4 + r;
                const size_t idx = (size_t)row * N + col;
                float v = acc[mt][nt][r] + bv;
                if constexpr (EPI == 0) {
                    ((short*)Cout)[idx] = f2bf(v);
                } else if constexpr (EPI == 1) {
                    ((short*)Cout)[idx] = f2bf(gelu_f(v));
                } else {
                    ((short*)Cout)[(size_t)blockIdx.z * M * N + idx] = f2bf(v);
                }
            }
        }
    }
}

// ---------------- causal flash attention (S^T formulation, K-split) ----------
// blockIdx.y in [0,24):
//   y in [0,8)   : qt = 8+y,  keys [0,1024)          -> partial0 (O0buf + m0/l0)
//   y in [8,16)  : qt = 15-y+8-8 = 15-(y-8) ... see code; keys [0,(qt+1)*128) direct
//   y in [16,24) : qt = 8+(23-y), keys [1024, (qt+1)*128) -> partial1 (aout + m1/l1)
// Longest blocks dispatch earliest. Partials are UNNORMALIZED (O' = sum p*v).
__global__ __launch_bounds__(256) void attn_kernel(
    const short* __restrict__ qkv, short* __restrict__ aout,
    short* __restrict__ O0buf, float* __restrict__ m0p, float* __restrict__ l0p,
    float* __restrict__ m1p, float* __restrict__ l1p) {
    __shared__ __align__(16) short smem[9216];   // Ks[64][72] | Vs[64][68]; reused as Ow
    short* Ks = smem;
    short* Vs = smem + 64 * 72;

    const int tid = threadIdx.x;
    const int wid = tid >> 6;
    const int lane = tid & 63;
    const int quad = lane >> 4;
    const int l16 = lane & 15;

    const int y = blockIdx.y;
    int qt, ktlo, kthi, mode;
    if (y < 8)       { qt = 8 + y;        ktlo = 0;  kthi = 16;             mode = 1; }
    else if (y < 16) { qt = 15 - y;       ktlo = 0;  kthi = (qt + 1) * 2;   mode = 0; }
    else             { qt = 8 + (23 - y); ktlo = 16; kthi = (qt + 1) * 2;   mode = 2; }
    const int q0 = qt * 128;
    const int bh = blockIdx.x;
    const int b = bh >> 4;
    const int h = bh & 15;

    const short* base = qkv + (size_t)b * 2048 * 3072 + h * 64;
    const int qrow_base = q0 + wid * 32;

    short8 qf[2][2];
#pragma unroll
    for (int qt_i = 0; qt_i < 2; qt_i++)
#pragma unroll
        for (int ks = 0; ks < 2; ks++)
            qf[qt_i][ks] = *(const short8*)(base +
                (size_t)(qrow_base + qt_i * 16 + l16) * 3072 + ks * 32 + quad * 8);

    floatx4 o[4][2] = {};           // O^T: [dt][qt_i]
    float mrow[2] = {-1e30f, -1e30f};
    float lrow[2] = {0.f, 0.f};
    const float SCL = 0.125f * 1.44269504f;  // raw-score -> log2 units

    for (int kt = ktlo; kt < kthi; kt++) {
        const int kt0 = kt * 64;
        {   // stage K[64][64] and V[64][64]
            const int r = tid >> 2;
            const int cg = (tid & 3) * 16;
            const short* krow = base + (size_t)(kt0 + r) * 3072 + 1024 + cg;
            const short* vrow = base + (size_t)(kt0 + r) * 3072 + 2048 + cg;
            *(uint4*)&Ks[r * 72 + cg] = ((const uint4*)krow)[0];
            *(uint4*)&Ks[r * 72 + cg + 8] = ((const uint4*)krow)[1];
            *(uint2*)&Vs[r * 68 + cg] = ((const uint2*)vrow)[0];
            *(uint2*)&Vs[r * 68 + cg + 4] = ((const uint2*)vrow)[1];
            *(uint2*)&Vs[r * 68 + cg + 8] = ((const uint2*)vrow)[2];
            *(uint2*)&Vs[r * 68 + cg + 12] = ((const uint2*)vrow)[3];
        }
        __syncthreads();
        if (kt0 <= qrow_base + 31) {
            floatx4 st[4][2] = {};
#pragma unroll
            for (int kti = 0; kti < 4; kti++) {
                const short8 kf0 = *(const short8*)&Ks[(kti * 16 + l16) * 72 + quad * 8];
                const short8 kf1 = *(const short8*)&Ks[(kti * 16 + l16) * 72 + 32 + quad * 8];
#pragma unroll
                for (int qt_i = 0; qt_i < 2; qt_i++) {
                    st[kti][qt_i] = MFMA16(kf0, qf[qt_i][0], st[kti][qt_i]);
                    st[kti][qt_i] = MFMA16(kf1, qf[qt_i][1], st[kti][qt_i]);
                }
            }
            const bool needmask = (kt0 + 63) > qrow_base;
            short8 pk[2][2];
#pragma unroll
            for (int qt_i = 0; qt_i < 2; qt_i++) {
                const int q = qrow_base + qt_i * 16 + l16;
                if (needmask) {
#pragma unroll
                    for (int kti = 0; kti < 4; kti++)
#pragma unroll
                        for (int r = 0; r < 4; r++)
                            if ((kt0 + kti * 16 + quad * 4 + r) > q) st[kti][qt_i][r] = -1e30f;
                }
                float mx = -1e30f;
#pragma unroll
                for (int kti = 0; kti < 4; kti++)
#pragma unroll
                    for (int r = 0; r < 4; r++) mx = fmaxf(mx, st[kti][qt_i][r]);
                mx = fmaxf(mx, __shfl_xor(mx, 16, 64));
                mx = fmaxf(mx, __shfl_xor(mx, 32, 64));
                const float mnew = fmaxf(mrow[qt_i], mx);
                const float alpha = exp2f((mrow[qt_i] - mnew) * SCL);
                mrow[qt_i] = mnew;
                const float nm = -mnew * SCL;
                float ps = 0.f;
#pragma unroll
                for (int kti = 0; kti < 4; kti++)
#pragma unroll
                    for (int r = 0; r < 4; r++) {
                        const float p = exp2f(fmaf(st[kti][qt_i][r], SCL, nm));
                        st[kti][qt_i][r] = p;
                        ps += p;
                    }
                ps += __shfl_xor(ps, 16, 64);
                ps += __shfl_xor(ps, 32, 64);
                lrow[qt_i] = lrow[qt_i] * alpha + ps;
#pragma unroll
                for (int dt = 0; dt < 4; dt++) o[dt][qt_i] *= alpha;
#pragma unroll
                for (int kti = 0; kti < 4; kti++)
#pragma unroll
                    for (int r = 0; r < 4; r++)
                        pk[kti >> 1][qt_i][(kti & 1) * 4 + r] = f2bf(st[kti][qt_i][r]);
            }
#pragma unroll
            for (int c = 0; c < 2; c++)
#pragma unroll
                for (int dt = 0; dt < 4; dt++) {
                    short8 vf;
#pragma unroll
                    for (int j = 0; j < 4; j++) {
                        vf[j]     = Vs[(c * 32 + quad * 4 + j) * 68 + dt * 16 + l16];
                        vf[4 + j] = Vs[(c * 32 + 16 + quad * 4 + j) * 68 + dt * 16 + l16];
                    }
                    o[dt][0] = MFMA16(vf, pk[c][0], o[dt][0]);
                    o[dt][1] = MFMA16(vf, pk[c][1], o[dt][1]);
                }
        }
        __syncthreads();
    }
    // epilogue: (maybe normalize), per-wave transpose O^T->O via LDS, store
    const int slot = (qt - 8) * 64 + bh;   // valid for modes 1/2
    short* Ow = smem + wid * (32 * 72);
    const float rl0 = (mode == 0) ? fast_rcp(lrow[0]) : 1.0f;
    const float rl1 = (mode == 0) ? fast_rcp(lrow[1]) : 1.0f;
#pragma unroll
    for (int dt = 0; dt < 4; dt++)
#pragma unroll
        for (int r = 0; r < 4; r++) {
            Ow[(l16) * 72 + dt * 16 + quad * 4 + r] = f2bf(o[dt][0][r] * rl0);
            Ow[(16 + l16) * 72 + dt * 16 + quad * 4 + r] = f2bf(o[dt][1][r] * rl1);
        }
    if (mode != 0 && quad == 0) {   // per-q m/l (q = qrow_base + qt_i*16 + l16)
        const int qi0 = slot * 128 + (qrow_base - q0) + l16;
        if (mode == 1) {
            m0p[qi0] = mrow[0]; l0p[qi0] = lrow[0];
            m0p[qi0 + 16] = mrow[1]; l0p[qi0 + 16] = lrow[1];
        } else {
            m1p[qi0] = mrow[0]; l1p[qi0] = lrow[0];
            m1p[qi0 + 16] = mrow[1]; l1p[qi0 + 16] = lrow[1];
        }
    }
    __asm__ volatile("s_waitcnt lgkmcnt(0)" ::: "memory");
    {
        const int ql = lane >> 1;
        const int h2 = lane & 1;
        short* orow;
        if (mode == 1)
            orow = O0buf + (size_t)slot * 8192 + (size_t)(wid * 32 + ql) * 64 + h2 * 32;
        else
            orow = aout + (size_t)(b * 2048 + q0 + wid * 32 + ql) * 1024 + h * 64 + h2 * 32;
#pragma unroll
        for (int s = 0; s < 4; s++)
            *(uint4*)(orow + s * 8) = *(const uint4*)&Ow[ql * 72 + h2 * 32 + s * 8];
    }
}

// ------- attention combine: aout = (O0*w0 + O1*w1) / (l0*w0 + l1*w1) ---------
__global__ __launch_bounds__(256) void attn_combine_kernel(
    const short* __restrict__ O0buf, short* __restrict__ aout,
    const float* __restrict__ m0p, const float* __restrict__ l0p,
    const float* __restrict__ m1p, const float* __restrict__ l1p) {
    const int slot = blockIdx.x;           // (qt-8)*64 + bh
    const int qt = 8 + (slot >> 6);
    const int bh = slot & 63;
    const int b = bh >> 4;
    const int h = bh & 15;
    const int t = threadIdx.x;
    const float SCL = 0.125f * 1.44269504f;
#pragma unroll
    for (int rep = 0; rep < 2; rep++) {
        const int ql = rep * 64 + (t >> 2);       // 0..127
        const int dg = (t & 3) * 16;
        const int qi = slot * 128 + ql;
        const float m0 = m0p[qi], l0 = l0p[qi], m1 = m1p[qi], l1 = l1p[qi];
        const float mm = fmaxf(m0, m1);
        const float w0 = exp2f((m0 - mm) * SCL);
        const float w1 = exp2f((m1 - mm) * SCL);
        const float rl = fast_rcp(fmaf(l0, w0, l1 * w1));
        const float f0 = w0 * rl, f1 = w1 * rl;
        const short* p0 = O0buf + (size_t)slot * 8192 + (size_t)ql * 64 + dg;
        short* pout = aout + (size_t)(b * 2048 + qt * 128 + ql) * 1024 + h * 64 + dg;
        union { uint4 v; unsigned short u[8]; } a0, a1, ov;
#pragma unroll
        for (int half = 0; half < 2; half++) {
            a0.v = ((const uint4*)p0)[half];
            a1.v = ((const uint4*)pout)[half];
#pragma unroll
            for (int j = 0; j < 8; j++)
                ov.u[j] = (unsigned short)f2bf(bf2f(a0.u[j]) * f0 + bf2f(a1.u[j]) * f1);
            ((uint4*)pout)[half] = ov.v;
        }
    }
}

// ---------------------------------------------------------------------------
extern "C" void kernel_launch(void* const* d_in, const int* in_sizes, int n_in,
                              void* d_out, int out_size, void* d_ws, size_t ws_size,
                              hipStream_t stream) {
    const float* x       = (const float*)d_in[0];
    const float* ln1_w   = (const float*)d_in[1];
    const float* ln1_b   = (const float*)d_in[2];
    const float* W_attn  = (const float*)d_in[3];
    const float* b_attn  = (const float*)d_in[4];
    const float* W_cproj = (const float*)d_in[5];
    const float* b_cproj = (const float*)d_in[6];
    const float* ln2_w   = (const float*)d_in[7];
    const float* ln2_b   = (const float*)d_in[8];
    const float* W_fc    = (const float*)d_in[9];
    const float* b_fc    = (const float*)d_in[10];
    const float* W_mproj = (const float*)d_in[11];
    const float* b_mproj = (const float*)d_in[12];

    char* ws = (char*)d_ws;
    short* W1t  = (short*)(ws + 0);
    short* W2t  = (short*)(ws + 6291456);
    short* W3t  = (short*)(ws + 8388608);
    short* W4t  = (short*)(ws + 16777216);
    short* h    = (short*)(ws + 25165824);
    short* aout = (short*)(ws + 41943040);
    short* big  = (short*)(ws + 58720256);   // qkv / cproj partials / fc-act
    // attention split-partial buffers inside the (dead) h region:
    short* O0buf = h;                                  // 512 * 8192 bf16 = 8 MB
    float* m0p = (float*)(ws + 25165824 + 8388608);           // 512*128 f32
    float* l0p = (float*)(ws + 25165824 + 8388608 + 262144);
    float* m1p = (float*)(ws + 25165824 + 8388608 + 524288);
    float* l1p = (float*)(ws + 25165824 + 8388608 + 786432);
    short* pbuf = h;                         // mproj partials [2][8192][1024]
    float* x2   = (float*)d_out;
    float* out  = (float*)d_out;

    dim3 tb(32, 8);
    hipLaunchKernelGGL(tcast_kernel, dim3(96, 32), tb, 0, stream, W_attn, W1t, 1024, 3072);
    hipLaunchKernelGGL(tcast_kernel, dim3(32, 32), tb, 0, stream, W_cproj, W2t, 1024, 1024);
    hipLaunchKernelGGL(tcast_kernel, dim3(128, 32), tb, 0, stream, W_fc, W3t, 1024, 4096);
    hipLaunchKernelGGL(tcast_kernel, dim3(32, 128), tb, 0, stream, W_mproj, W4t, 4096, 1024);

    hipLaunchKernelGGL(ln_kernel, dim3(8192), dim3(256), 0, stream, x, ln1_w, ln1_b, h);

    hipLaunchKernelGGL((gemm_kernel<0>), dim3(24, 64, 1), dim3(256), 0, stream,
                       h, W1t, b_attn, (void*)big,
                       8192, 3072, 1024, 1024, 1024);

    hipLaunchKernelGGL(attn_kernel, dim3(64, 24), dim3(256), 0, stream,
                       big, aout, O0buf, m0p, l0p, m1p, l1p);
    hipLaunchKernelGGL(attn_combine_kernel, dim3(512), dim3(256), 0, stream,
                       O0buf, aout, m0p, l0p, m1p, l1p);

    // cproj: K-split x2 -> bf16 partials in big (qkv dead), then fused reduce+ln2.
    hipLaunchKernelGGL((gemm_kernel<3>), dim3(8, 64, 2), dim3(256), 0, stream,
                       aout, W2t, (const float*)nullptr, (void*)big,
                       8192, 1024, 512, 1024, 1024);
    hipLaunchKernelGGL(reduce_ln_kernel, dim3(8192), dim3(256), 0, stream,
                       (const unsigned short*)big,
                       (const unsigned short*)(big + (size_t)8192 * 1024),
                       b_cproj, x, x2, ln2_w, ln2_b, h);

    hipLaunchKernelGGL((gemm_kernel<1>), dim3(32, 64, 1), dim3(256), 0, stream,
                       h, W3t, b_fc, (void*)big,
                       8192, 4096, 1024, 1024, 1024);

    // mproj: K-split x2 -> bf16 partials (h+aout region), then fused reduce.
    hipLaunchKernelGGL((gemm_kernel<3>), dim3(8, 64, 2), dim3(256), 0, stream,
                       big, W4t, (const float*)nullptr, (void*)pbuf,
                       8192, 1024, 2048, 4096, 4096);
    hipLaunchKernelGGL(reduce_kernel, dim3(8192), dim3(256), 0, stream,
                       (const unsigned short*)pbuf,
                       (const unsigned short*)(pbuf + (size_t)8192 * 1024),
                       b_mproj, x2, out);
}